// Round 13
// baseline (3205.321 us; speedup 1.0000x reference)
//
#include <hip/hip_runtime.h>

// LSTM decoder B=64,S=512,D=512,H=512,L=2 — Round 13: fine-grained dataflow.
// 8 waves = K-eighths (chunks 4w..4w+3, ALL 4 gates each):
//   - A fragments loaded per-wave straight from L3 (sc1) into regs: no LDS
//     staging, no staging barrier; disjoint chunks -> no redundant traffic.
//   - wreg: 4 gates x 4 chunks = 16 short8 pinned (R11-proven).
//   - ONE __syncthreads per step (Gp double-buffered by step parity).
// Per-(block,cell-wave) subflags posted after that wave's own vmcnt(0) drain;
// consumers poll only their 8 producer blocks (+ role1 anti-dep gate for role0).
// h buffers 4-deep packed bf16; union-of-polls bounds block skew <= ~1 step.

#define NB 64
#define NS 512
#define ND 512
#define NH 512

typedef __attribute__((ext_vector_type(8))) short short8;
typedef __attribute__((ext_vector_type(4))) float f32x4;
typedef __attribute__((ext_vector_type(4))) unsigned int u32x4;

// ---- ws layout (bytes) ----
#define WPK_OFF   0                 // 8,388,608
#define H0_OFF    8388608           // 4 bufs * 65536 B (bf16 64x512)
#define H1_OFF    8650752           // 4 bufs * 65536 B
#define FLAGS_OFF 8912896           // 4 groups * 256 u32 = 4 KB
#define WPK_ELEMS_PER_ROLE (128 * 32 * 512)

__device__ __forceinline__ unsigned int pack2bf(float a, float b) {
    unsigned int ua = __builtin_bit_cast(unsigned int, a);
    unsigned int ub = __builtin_bit_cast(unsigned int, b);
    ua += 0x7fffu + ((ua >> 16) & 1u);   // RNE
    ub += 0x7fffu + ((ub >> 16) & 1u);
    return (ua >> 16) | (ub & 0xffff0000u);
}
__device__ __forceinline__ unsigned short bf16r(float a) {
    unsigned int ua = __builtin_bit_cast(unsigned int, a);
    ua += 0x7fffu + ((ua >> 16) & 1u);
    return (unsigned short)(ua >> 16);
}

__device__ __forceinline__ void st_h32(unsigned int* p, unsigned int v) {
    __hip_atomic_store(p, v, __ATOMIC_RELAXED, __HIP_MEMORY_SCOPE_AGENT);
}
__device__ __forceinline__ void st_flag(unsigned int* p, unsigned int v) {
    __hip_atomic_store(p, v, __ATOMIC_RELAXED, __HIP_MEMORY_SCOPE_AGENT);
}

// 4 flag words, L3-coherent, one waitcnt
__device__ __forceinline__ u32x4 ld_flags4(const unsigned int* p) {
    u32x4 r;
    asm volatile("global_load_dwordx4 %0, %1, off sc0 sc1\n\ts_waitcnt vmcnt(0)"
                 : "=&v"(r) : "v"(p) : "memory");
    return r;
}
// 4 A-fragments (4x16B), L3-coherent, one waitcnt
__device__ __forceinline__ void ld4x16(const unsigned short* p0, const unsigned short* p1,
                                       const unsigned short* p2, const unsigned short* p3,
                                       short8& a0, short8& a1, short8& a2, short8& a3) {
    asm volatile(
        "global_load_dwordx4 %0, %4, off sc0 sc1\n\t"
        "global_load_dwordx4 %1, %5, off sc0 sc1\n\t"
        "global_load_dwordx4 %2, %6, off sc0 sc1\n\t"
        "global_load_dwordx4 %3, %7, off sc0 sc1\n\t"
        "s_waitcnt vmcnt(0)"
        : "=&v"(a0), "=&v"(a1), "=&v"(a2), "=&v"(a3)
        : "v"(p0), "v"(p1), "v"(p2), "v"(p3)
        : "memory");
    __builtin_amdgcn_sched_barrier(0);
}

// Repack weights into MFMA B-fragment order:
// fragment (r, nt, k0i), lane l, elem j: B[k][n], n = nt*16+(l&15), k = k0i*32+(l>>4)*8+j
__global__ void prep_weights_k(const float* __restrict__ W_ih,
                               const float* __restrict__ W_hh,
                               unsigned int* __restrict__ wpk_u32) {
    long long gid = (long long)blockIdx.x * blockDim.x + threadIdx.x; // 524288
    int l   = (int)(gid & 63);
    int k0i = (int)((gid >> 6) & 31);
    int nt  = (int)((gid >> 11) & 127);
    int r   = (int)(gid >> 18);
    int n = nt * 16 + (l & 15);
    int k = k0i * 32 + ((l >> 4) << 3);
    const float* src;
    if (k < 512) src = W_ih + ((long long)r * 2048 + n) * 512 + k;
    else         src = W_hh + ((long long)r * 2048 + n) * 512 + (k - 512);
    uint4 v;
    v.x = pack2bf(src[0], src[1]);
    v.y = pack2bf(src[2], src[3]);
    v.z = pack2bf(src[4], src[5]);
    v.w = pack2bf(src[6], src[7]);
    ((uint4*)wpk_u32)[gid] = v;
}

__global__ void prep_state_k(const float* __restrict__ eh,
                             unsigned short* __restrict__ h0base,
                             unsigned short* __restrict__ h1base,
                             unsigned int* __restrict__ flags) {
    int i = blockIdx.x * blockDim.x + threadIdx.x;  // 32768
    if (i < NB * NH) {
        unsigned short hb = bf16r(eh[i]);
        (h0base + 3 * 32768)[i] = hb;   // h0_{-1} -> buf (-1)&3 = 3
        (h1base + 3 * 32768)[i] = hb;   // h1_{-1} -> buf (-1)&3 = 3
    }
    if (i < 1024) flags[i] = 0;
}

__global__ __launch_bounds__(512, 1)
void lstm_persist_k(const float* __restrict__ input,
                    const float* __restrict__ enc_c,
                    const float* __restrict__ b_ih,
                    const float* __restrict__ b_hh,
                    const unsigned short* __restrict__ wpk,
                    unsigned short* __restrict__ h0base,
                    unsigned short* __restrict__ h1base,
                    float* __restrict__ out,
                    unsigned int* __restrict__ flags) {
    __shared__ float Gp[2][8][4][16][17];   // [parity][wave][gate][row][col]

    const int bid  = blockIdx.x;
    const int role = bid >> 7;             // 0: layer0(i), 1: layer1(i-1)
    const int lb   = bid & 127;
    const int ms   = lb >> 5;              // batch group 0..3
    const int us   = lb & 31;              // unit block 0..31
    const int m0   = ms << 4;
    const int tid  = threadIdx.x;
    const int lane = tid & 63;
    const int w    = __builtin_amdgcn_readfirstlane(tid >> 6);  // K-eighth 0..7
    const int wh   = (w >= 4) ? (w - 4) : 0;

    const int row  = m0 + (lane & 15);
    const int col8 = (lane >> 4) << 3;

    // ---- pin B-fragments: gate g, chunk jj = w*4+jj -> wreg[g*4+jj] ----
    short8 wreg[16];
    #pragma unroll
    for (int g2 = 0; g2 < 4; ++g2)
        #pragma unroll
        for (int jj = 0; jj < 4; ++jj)
            wreg[g2 * 4 + jj] = *(const short8*)(wpk
                + (long long)role * WPK_ELEMS_PER_ROLE
                + (long long)(g2 * 32 + us) * (32 * 512)
                + (long long)(w * 4 + jj) * 512 + lane * 8);
    #pragma unroll
    for (int j = 0; j < 16; ++j)
        asm volatile("" : "+v"(wreg[j]));

    // ---- flags: 256 u32 per group: [role][us][cell-wave] ----
    unsigned int* fb = flags + (ms << 8);
    unsigned int* myflag = fb + role * 128 + us * 4 + w;   // valid for w<4
    const unsigned int* pollp;
    {
        int idx;
        if (role == 0)      idx = (lane < 8) ? (wh * 32 + lane * 4)
                                : (lane < 40 ? (128 + (lane - 8) * 4) : ((lane & 7) * 4));
        else if (w < 4)     idx = (lane < 8) ? (w * 32 + lane * 4) : ((lane & 7) * 4);
        else                idx = (lane < 8) ? (128 + wh * 32 + lane * 4) : (128 + (lane & 7) * 4);
        pollp = fb + idx;
    }

    // ---- cell state + biases (threads 0..255 own the 256 cells) ----
    const int m_l = (tid >> 4) & 15, u_l = tid & 15;
    const int bcell = m0 + m_l;
    const int ucell = us * 16 + u_l;
    float cReg = 0.f, bias_i = 0.f, bias_f = 0.f, bias_g = 0.f, bias_o = 0.f;
    if (tid < 256) {
        cReg = enc_c[bcell * NH + ucell];
        const long long br = (long long)role * 2048;
        bias_i = b_ih[br + 0 * 512 + ucell] + b_hh[br + 0 * 512 + ucell];
        bias_f = b_ih[br + 1 * 512 + ucell] + b_hh[br + 1 * 512 + ucell];
        bias_g = b_ih[br + 2 * 512 + ucell] + b_hh[br + 2 * 512 + ucell];
        bias_o = b_ih[br + 3 * 512 + ucell] + b_hh[br + 3 * 512 + ucell];
    }

    // ---- role0 x-waves (w<4): prefetch x(0) fragments (fp32) ----
    float4 xpA[4], xpB[4];
    if (role == 0 && w < 4) {
        #pragma unroll
        for (int jj = 0; jj < 4; ++jj) {
            const float* s = input + (long long)row * (NS * ND)
                                   + (w * 4 + jj) * 32 + col8;
            xpA[jj] = *(const float4*)s;
            xpB[jj] = *(const float4*)(s + 4);
        }
    }

    for (int i = 0; i <= NS; ++i) {
        const int par = i & 1;
        const bool active = (role == 0) ? (i < NS) : (i >= 1);

        if (active) {
            short8 a[4];
            if (role == 0 && w < 4) {
                // x chunks from prefetched regs
                #pragma unroll
                for (int jj = 0; jj < 4; ++jj) {
                    u32x4 u;
                    u.x = pack2bf(xpA[jj].x, xpA[jj].y);
                    u.y = pack2bf(xpA[jj].z, xpA[jj].w);
                    u.z = pack2bf(xpB[jj].x, xpB[jj].y);
                    u.w = pack2bf(xpB[jj].z, xpB[jj].w);
                    a[jj] = __builtin_bit_cast(short8, u);
                }
            } else {
                // poll just this wave's producers (+ gate for role0)
                unsigned thr;
                if (role == 0)
                    thr = (lane < 8) ? (unsigned)i
                        : (lane < 40 ? (unsigned)(i >= 2 ? i - 2 : 0) : 0u);
                else if (w < 4)
                    thr = (lane < 8) ? (unsigned)i : 0u;
                else
                    thr = (lane < 8 && i >= 2) ? (unsigned)i : 0u;
                for (;;) {
                    u32x4 f = ld_flags4(pollp);
                    unsigned mn  = f.x < f.y ? f.x : f.y;
                    unsigned mn2 = f.z < f.w ? f.z : f.w;
                    mn = mn < mn2 ? mn : mn2;
                    if (__ballot(mn >= thr) == 0xFFFFFFFFFFFFFFFFULL) break;
                }
                // direct L3 -> reg fragment loads (disjoint chunks)
                const unsigned short* hsrc;
                int ubase;
                if (role == 0)      { hsrc = h0base + (((i - 1) & 3) << 15); ubase = wh * 128; }
                else if (w < 4)     { hsrc = h0base + (((i - 1) & 3) << 15); ubase = w * 128; }
                else                { hsrc = h1base + (((i - 2) & 3) << 15); ubase = wh * 128; }
                const unsigned short* pr = hsrc + row * 512 + ubase + col8;
                ld4x16(pr, pr + 32, pr + 64, pr + 96, a[0], a[1], a[2], a[3]);
            }

            // ---- 16 MFMAs: 4 gates x 4 chunks, B pinned in regs ----
            f32x4 acc[4];
            #pragma unroll
            for (int g2 = 0; g2 < 4; ++g2) acc[g2] = (f32x4){0.f, 0.f, 0.f, 0.f};
            #pragma unroll
            for (int jj = 0; jj < 4; ++jj)
                #pragma unroll
                for (int g2 = 0; g2 < 4; ++g2)
                    acc[g2] = __builtin_amdgcn_mfma_f32_16x16x32_bf16(
                        a[jj], wreg[g2 * 4 + jj], acc[g2], 0, 0, 0);

            // ---- partial gates to Gp[par] ----
            {
                int rbase = (lane >> 4) * 4, cidx = lane & 15;
                #pragma unroll
                for (int g2 = 0; g2 < 4; ++g2)
                    #pragma unroll
                    for (int r = 0; r < 4; ++r)
                        Gp[par][w][g2][rbase + r][cidx] = acc[g2][r];
            }
        }

        __syncthreads();   // the ONE barrier: Gp[par] complete

        if (active && tid < 256) {
            float s0 = bias_i, s1 = bias_f, s2 = bias_g, s3 = bias_o;
            #pragma unroll
            for (int w8 = 0; w8 < 8; ++w8) {
                s0 += Gp[par][w8][0][m_l][u_l];
                s1 += Gp[par][w8][1][m_l][u_l];
                s2 += Gp[par][w8][2][m_l][u_l];
                s3 += Gp[par][w8][3][m_l][u_l];
            }
            float ii = 1.f / (1.f + expf(-s0));
            float ff = 1.f / (1.f + expf(-s1));
            float gv = tanhf(s2);
            float oo = 1.f / (1.f + expf(-s3));
            cReg = ff * cReg + ii * gv;
            float hn = oo * tanhf(cReg);

            // packed bf16 h store (sc1), per-wave drain, subflag post
            float hn_p = __shfl_xor(hn, 1);
            unsigned short* hbuf = (role == 0)
                ? h0base + ((i & 3) << 15)
                : h1base + (((i - 1) & 3) << 15);
            if ((u_l & 1) == 0)
                st_h32((unsigned int*)hbuf + ((bcell * 512 + ucell) >> 1),
                       pack2bf(hn, hn_p));
            __builtin_amdgcn_sched_barrier(0);
            asm volatile("s_waitcnt vmcnt(0)" ::: "memory");
            __builtin_amdgcn_sched_barrier(0);
            if (lane == 0) st_flag(myflag, (unsigned int)(i + 1));

            if (role == 1) {
                int s = i - 1;
                out[(long long)bcell * (NS * NH) + (long long)s * NH + ucell] = hn;
                if (i == NS) {
                    float* dst = out + (long long)NB * NS * NH;
                    dst[bcell * NH + ucell] = hn;
                    dst[NB * NH + bcell * NH + ucell] = cReg;
                }
            }
            // prefetch next x fragments (after flag: not in drain set)
            if (role == 0 && i + 1 < NS) {
                #pragma unroll
                for (int jj = 0; jj < 4; ++jj) {
                    const float* s = input + (long long)row * (NS * ND)
                                           + (long long)(i + 1) * ND
                                           + (w * 4 + jj) * 32 + col8;
                    xpA[jj] = *(const float4*)s;
                    xpB[jj] = *(const float4*)(s + 4);
                }
            }
        }
    }
}

extern "C" void kernel_launch(void* const* d_in, const int* in_sizes, int n_in,
                              void* d_out, int out_size, void* d_ws, size_t ws_size,
                              hipStream_t stream) {
    const float* input = (const float*)d_in[0];
    const float* enc_h = (const float*)d_in[1];
    const float* enc_c = (const float*)d_in[2];
    const float* W_ih  = (const float*)d_in[3];
    const float* W_hh  = (const float*)d_in[4];
    const float* b_ih  = (const float*)d_in[5];
    const float* b_hh  = (const float*)d_in[6];
    float* out = (float*)d_out;
    unsigned char* ws = (unsigned char*)d_ws;

    unsigned short* wpk    = (unsigned short*)(ws + WPK_OFF);
    unsigned short* h0base = (unsigned short*)(ws + H0_OFF);
    unsigned short* h1base = (unsigned short*)(ws + H1_OFF);
    unsigned int*   flags  = (unsigned int*)(ws + FLAGS_OFF);

    prep_weights_k<<<2048, 256, 0, stream>>>(W_ih, W_hh, (unsigned int*)wpk);
    prep_state_k<<<128, 256, 0, stream>>>(enc_h, h0base, h1base, flags);
    lstm_persist_k<<<256, 512, 0, stream>>>(input, enc_c, b_ih, b_hh, wpk,
                                            h0base, h1base, out, flags);
}

// Round 14
// 2296.022 us; speedup vs baseline: 1.3960x; 1.3960x over previous
//
#include <hip/hip_runtime.h>

// LSTM decoder B=64,S=512,D=512,H=512,L=2 — Round 14: XCD-local tagged exchange.
// Decode: xcd=bid&7 -> grp=xcd>>1, role=xcd&1, us=bid>>3 (32 blocks per XCD =
// one (grp,role) slice; 4MB weight slice fits its L2). Local chains (h0->h0,
// h1->h1): tagged u32 words (epoch<<16|bf16), plain store -> local L2, sc0
// load + tag validate (no flags, no drains on the critical path).
// Truth copies h0x/h1x (packed bf16, SEPARATE buffers, sc1) + R11 flag
// protocol serve (a) role1's cross-layer x reads, (b) sticky fallback if the
// XCD mapping assumption fails -> correctness mapping-independent.
// Anti-dep: 8-deep buffers + every-4-step gate (>= i-3) => skew <= 6 < 7.
// Compute identical to R11: K-split 8 waves, weights pinned in 64 VGPRs.

#define NB 64
#define NS 512
#define ND 512
#define NH 512

typedef __attribute__((ext_vector_type(8))) short short8;
typedef __attribute__((ext_vector_type(4))) float f32x4;
typedef __attribute__((ext_vector_type(4))) unsigned int u32x4;
typedef unsigned long long ull;

// ---- ws layout (bytes) ----
#define WPK_OFF    0                 // 8,388,608
#define H0LOC_OFF  8388608           // 4 grp * 8 buf * 16*512 u32 = 1,048,576
#define H1LOC_OFF  9437184           // 1,048,576
#define H0X_OFF    10485760          // 8 buf * 64*512 bf16 = 524,288
#define H1X_OFF    11010048          // 524,288
#define FLAGS_OFF  11534336          // 256 u32
#define WPK_ELEMS_PER_ROLE (128 * 32 * 512)

__device__ __forceinline__ unsigned int pack2bf(float a, float b) {
    unsigned int ua = __builtin_bit_cast(unsigned int, a);
    unsigned int ub = __builtin_bit_cast(unsigned int, b);
    ua += 0x7fffu + ((ua >> 16) & 1u);   // RNE
    ub += 0x7fffu + ((ub >> 16) & 1u);
    return (ua >> 16) | (ub & 0xffff0000u);
}
__device__ __forceinline__ unsigned short bf16r(float a) {
    unsigned int ua = __builtin_bit_cast(unsigned int, a);
    ua += 0x7fffu + ((ua >> 16) & 1u);
    return (unsigned short)(ua >> 16);
}

__device__ __forceinline__ ull ld_h64(const void* p) {
    return __hip_atomic_load((const ull*)p, __ATOMIC_RELAXED, __HIP_MEMORY_SCOPE_AGENT);
}
__device__ __forceinline__ void st_h32(unsigned int* p, unsigned int v) {
    __hip_atomic_store(p, v, __ATOMIC_RELAXED, __HIP_MEMORY_SCOPE_AGENT);
}
__device__ __forceinline__ unsigned int ld_flag(const unsigned int* p) {
    return __hip_atomic_load(p, __ATOMIC_RELAXED, __HIP_MEMORY_SCOPE_AGENT);
}
__device__ __forceinline__ void st_flag(unsigned int* p, unsigned int v) {
    __hip_atomic_store(p, v, __ATOMIC_RELAXED, __HIP_MEMORY_SCOPE_AGENT);
}

__device__ __forceinline__ bool tag8_ok(const u32x4& a, const u32x4& b, unsigned int T) {
    unsigned int m = ((a.x >> 16) ^ T) | ((a.y >> 16) ^ T)
                   | ((a.z >> 16) ^ T) | ((a.w >> 16) ^ T)
                   | ((b.x >> 16) ^ T) | ((b.y >> 16) ^ T)
                   | ((b.z >> 16) ^ T) | ((b.w >> 16) ^ T);
    return m == 0;
}
__device__ __forceinline__ u32x4 pack8(const u32x4& a, const u32x4& b) {
    u32x4 r;
    r.x = (a.x & 0xFFFFu) | (a.y << 16);
    r.y = (a.z & 0xFFFFu) | (a.w << 16);
    r.z = (b.x & 0xFFFFu) | (b.y << 16);
    r.w = (b.z & 0xFFFFu) | (b.w << 16);
    return r;
}

// 2 tagged slots (2x32B) via sc0 (local-L2), single waitcnt
__device__ __forceinline__ void load2_sc0(const unsigned int* q0, const unsigned int* q1,
                                          u32x4& a0, u32x4& b0, u32x4& a1, u32x4& b1) {
    asm volatile(
        "global_load_dwordx4 %0, %4, off sc0\n\t"
        "global_load_dwordx4 %1, %4, off offset:16 sc0\n\t"
        "global_load_dwordx4 %2, %5, off sc0\n\t"
        "global_load_dwordx4 %3, %5, off offset:16 sc0\n\t"
        "s_waitcnt vmcnt(0)"
        : "=&v"(a0), "=&v"(b0), "=&v"(a1), "=&v"(b1)
        : "v"(q0), "v"(q1) : "memory");
    __builtin_amdgcn_sched_barrier(0);
}
// one 16B fragment via sc1 (L3 truth copy)
__device__ __forceinline__ u32x4 ld16_sc1(const void* p) {
    u32x4 r;
    asm volatile("global_load_dwordx4 %0, %1, off sc0 sc1\n\ts_waitcnt vmcnt(0)"
                 : "=&v"(r) : "v"(p) : "memory");
    return r;
}

// Repack weights into MFMA B-fragment order:
// fragment (r, nt, k0i), lane l, elem j: B[k][n], n = nt*16+(l&15), k = k0i*32+(l>>4)*8+j
__global__ void prep_weights_k(const float* __restrict__ W_ih,
                               const float* __restrict__ W_hh,
                               unsigned int* __restrict__ wpk_u32) {
    long long gid = (long long)blockIdx.x * blockDim.x + threadIdx.x; // 524288
    int l   = (int)(gid & 63);
    int k0i = (int)((gid >> 6) & 31);
    int nt  = (int)((gid >> 11) & 127);
    int r   = (int)(gid >> 18);
    int n = nt * 16 + (l & 15);
    int k = k0i * 32 + ((l >> 4) << 3);
    const float* src;
    if (k < 512) src = W_ih + ((long long)r * 2048 + n) * 512 + k;
    else         src = W_hh + ((long long)r * 2048 + n) * 512 + (k - 512);
    uint4 v;
    v.x = pack2bf(src[0], src[1]);
    v.y = pack2bf(src[2], src[3]);
    v.z = pack2bf(src[4], src[5]);
    v.w = pack2bf(src[6], src[7]);
    ((uint4*)wpk_u32)[gid] = v;
}

// Clear all tagged buffers every call (kills stale tags across graph replays);
// seed h_{-1} (tag 0) into buf 7; init truth copies buf 7; zero flags.
__global__ void prep_state_k(const float* __restrict__ eh,
                             unsigned int* __restrict__ h0loc,
                             unsigned int* __restrict__ h1loc,
                             unsigned short* __restrict__ h0x,
                             unsigned short* __restrict__ h1x,
                             unsigned int* __restrict__ flags) {
    int gid = blockIdx.x * blockDim.x + threadIdx.x;  // 262144
    if (gid < 262144) {
        int grp = gid >> 16;
        int rem = gid & 65535;
        int buf = rem >> 13;
        int idx = rem & 8191;
        unsigned int v = 0;
        if (buf == 7) {
            int row = idx >> 9, u = idx & 511;
            v = (unsigned int)bf16r(eh[(grp * 16 + row) * 512 + u]);
        }
        h0loc[gid] = v;
        h1loc[gid] = v;
    }
    if (gid < 32768) {
        unsigned short hb = bf16r(eh[gid]);
        h0x[7 * 32768 + gid] = hb;
        h1x[7 * 32768 + gid] = hb;
    }
    if (gid < 256) flags[gid] = 0;
}

__global__ __launch_bounds__(512, 1)
void lstm_persist_k(const float* __restrict__ input,
                    const float* __restrict__ enc_c,
                    const float* __restrict__ b_ih,
                    const float* __restrict__ b_hh,
                    const unsigned short* __restrict__ wpk,
                    unsigned int* __restrict__ h0loc,
                    unsigned int* __restrict__ h1loc,
                    unsigned short* __restrict__ h0x,
                    unsigned short* __restrict__ h1x,
                    float* __restrict__ out,
                    unsigned int* __restrict__ flags) {
    __shared__ alignas(16) unsigned char smem[32768];   // A tile (fragment-packed)
    __shared__ float Gp[8][16][17];                     // partial gates per wave
    const int bid  = blockIdx.x;
    const int xcd  = bid & 7;
    const int grp  = xcd >> 1;            // batch group 0..3 (16 rows)
    const int role = xcd & 1;             // 0: layer0(i), 1: layer1(i-1)
    const int us   = bid >> 3;            // unit block 0..31
    const int m0   = grp << 4;
    const int tid  = threadIdx.x;
    const int lane = tid & 63;
    const int w    = tid >> 6;            // wave 0..7
    const int g    = __builtin_amdgcn_readfirstlane(w & 3);   // gate
    const int kh   = __builtin_amdgcn_readfirstlane(w >> 2);  // K-half

    const unsigned short* wp = wpk + (long long)role * WPK_ELEMS_PER_ROLE
                             + (long long)(g * 32 + us) * (32 * 512)
                             + (long long)kh * 16 * 512;
    const unsigned char* aBase = smem + kh * 16384;

    // ---- pin this wave's 16 B-fragments in registers (once) ----
    short8 wreg[16];
    #pragma unroll
    for (int j = 0; j < 16; ++j)
        wreg[j] = *(const short8*)(wp + j * 512 + lane * 8);
    #pragma unroll
    for (int j = 0; j < 16; ++j)
        asm volatile("" : "+v"(wreg[j]));

    unsigned int* fb = flags + (grp << 6);            // group's 64 flags
    unsigned int* myflag = fb + (role << 5) + us;

    // ---- cell state + biases (threads 0..255 own the 256 cells) ----
    const int m_l = (tid >> 4) & 15, u_l = tid & 15;
    const int bcell = m0 + m_l;
    const int ucell = us * 16 + u_l;
    float cReg = 0.f, bias_i = 0.f, bias_f = 0.f, bias_g = 0.f, bias_o = 0.f;
    if (tid < 256) {
        cReg = enc_c[bcell * NH + ucell];
        const long long br = (long long)role * 2048;
        bias_i = b_ih[br + 0 * 512 + ucell] + b_hh[br + 0 * 512 + ucell];
        bias_f = b_ih[br + 1 * 512 + ucell] + b_hh[br + 1 * 512 + ucell];
        bias_g = b_ih[br + 2 * 512 + ucell] + b_hh[br + 2 * 512 + ucell];
        bias_o = b_ih[br + 3 * 512 + ucell] + b_hh[br + 3 * 512 + ucell];
    }

    // staging geometry
    const int srow  = tid & 15;
    const int skoff = ((tid >> 4) & 3) << 3;
    const int uoff  = (w << 5) + skoff;               // h-part unit base for this thread
    int lbudget = 24;                                 // sticky local-try budget

    // ---- role0: prefetch x(0) into registers ----
    float4 xp[4];
    if (role == 0) {
        #pragma unroll
        for (int j2 = 0; j2 < 2; ++j2) {
            int sid = j2 * 512 + tid;
            int k = (sid >> 6) * 32 + skoff;
            const float* s = input + (long long)(m0 + srow) * (NS * ND) + k;
            xp[2 * j2]     = *(const float4*)s;
            xp[2 * j2 + 1] = *(const float4*)(s + 4);
        }
    }

    for (int i = 0; i <= NS; ++i) {
        const bool active = (role == 0) ? (i < NS) : (i >= 1);
        const bool gate = ((i & 3) == 0) && (i >= 4);

        if (active) {
            // ---- A: role0 pre-poll x staging (regs -> LDS x-region) ----
            if (role == 0) {
                #pragma unroll
                for (int j2 = 0; j2 < 2; ++j2) {
                    int sid = j2 * 512 + tid;
                    float4 lo = xp[2 * j2], hi = xp[2 * j2 + 1];
                    uint4 val;
                    val.x = pack2bf(lo.x, lo.y);
                    val.y = pack2bf(lo.z, lo.w);
                    val.z = pack2bf(hi.x, hi.y);
                    val.w = pack2bf(hi.z, hi.w);
                    *(uint4*)(smem + sid * 16) = val;
                }
            }

            // ---- B: polls (all waves; no extra barrier) ----
            if (role == 1) {
                unsigned int thr = (lane < 32) ? (unsigned int)i
                                 : (gate ? (unsigned int)(i - 3) : 0u);
                const unsigned int* fp = fb + lane;
                for (;;) {
                    unsigned int v = ld_flag(fp);
                    if (__ballot(v >= thr) == 0xFFFFFFFFFFFFFFFFULL) break;
                    __builtin_amdgcn_s_sleep(1);
                }
            } else if (gate) {
                unsigned int thr = (unsigned int)(i - 3);
                const unsigned int* fp = fb + lane;
                for (;;) {
                    unsigned int v = ld_flag(fp);
                    if (__ballot(v >= thr) == 0xFFFFFFFFFFFFFFFFULL) break;
                    __builtin_amdgcn_s_sleep(1);
                }
            }

            // ---- C1: role1 x-part = h0x (sc1, flag-gated: proven R11 path) ----
            if (role == 1) {
                const unsigned short* xh = h0x + (((i - 1) & 7) << 15);
                #pragma unroll
                for (int j2 = 0; j2 < 2; ++j2) {
                    int sid = j2 * 512 + tid;
                    int k = (sid >> 6) * 32 + skoff;
                    const ull* p = (const ull*)(xh + (long long)(m0 + srow) * 512 + k);
                    ull lo = ld_h64(p);
                    ull hi = ld_h64(p + 1);
                    uint4 val;
                    val.x = (unsigned int)lo; val.y = (unsigned int)(lo >> 32);
                    val.z = (unsigned int)hi; val.w = (unsigned int)(hi >> 32);
                    *(uint4*)(smem + sid * 16) = val;
                }
            }

            // ---- C2: h-part — local tagged sc0 read, sticky sc1 fallback ----
            {
                const unsigned int* lbase;
                const unsigned short* xbase;
                const unsigned int* fpb;
                unsigned int T;
                if (role == 0) {
                    lbase = h0loc + grp * 65536 + (((i - 1) & 7) << 13);
                    xbase = h0x + (((i - 1) & 7) << 15);
                    fpb = fb;  T = (unsigned int)i;
                } else {
                    lbase = h1loc + grp * 65536 + (((i - 2) & 7) << 13);
                    xbase = h1x + (((i - 2) & 7) << 15);
                    fpb = fb + 32;  T = (unsigned int)(i - 1);
                }
                const unsigned int* q0 = lbase + srow * 512 + uoff;
                const unsigned int* q1 = q0 + 256;
                u32x4 a0, b0, a1, b1;
                bool got = false;
                for (int t2 = 0; t2 < lbudget; ++t2) {
                    load2_sc0(q0, q1, a0, b0, a1, b1);
                    if (tag8_ok(a0, b0, T) && tag8_ok(a1, b1, T)) { got = true; break; }
                }
                u32x4 f1, f2;
                if (got) {
                    f1 = pack8(a0, b0);
                    f2 = pack8(a1, b1);
                } else {
                    lbudget = 0;   // sticky: local path dead for this thread
                    int usp = 2 * w + (skoff >= 16 ? 1 : 0);
                    const unsigned int* fp1 = fpb + usp;
                    const unsigned int* fp2 = fpb + usp + 16;
                    while (ld_flag(fp1) < (unsigned int)i) __builtin_amdgcn_s_sleep(2);
                    while (ld_flag(fp2) < (unsigned int)i) __builtin_amdgcn_s_sleep(2);
                    const unsigned short* xq = xbase + (long long)(m0 + srow) * 512 + uoff;
                    f1 = ld16_sc1(xq);
                    f2 = ld16_sc1(xq + 256);
                }
                *(u32x4*)(smem + (1024 + tid) * 16) = f1;
                *(u32x4*)(smem + (1536 + tid) * 16) = f2;
            }
            __syncthreads();   // sync1: A staged

            // ---- GEMM: wave (g,kh) -> 16 MFMAs, B from registers ----
            f32x4 acc0 = {0.f,0.f,0.f,0.f}, acc1 = {0.f,0.f,0.f,0.f};
            #pragma unroll
            for (int j = 0; j < 16; j += 2) {
                short8 a0 = *(const short8*)(aBase + (j + 0) * 1024 + lane * 16);
                short8 a1 = *(const short8*)(aBase + (j + 1) * 1024 + lane * 16);
                acc0 = __builtin_amdgcn_mfma_f32_16x16x32_bf16(a0, wreg[j + 0], acc0, 0, 0, 0);
                acc1 = __builtin_amdgcn_mfma_f32_16x16x32_bf16(a1, wreg[j + 1], acc1, 0, 0, 0);
            }
            f32x4 accS = acc0 + acc1;
            {
                int u_g  = lane & 15;
                int mrow = (lane >> 4) * 4;
                #pragma unroll
                for (int r = 0; r < 4; ++r)
                    Gp[w][mrow + r][u_g] = accS[r];
            }
            __syncthreads();   // sync2: Gp ready

            // ---- fused LSTM cell (tid<256), tagged local + sc1 truth stores ----
            if (tid < 256) {
                float s0 = Gp[0][m_l][u_l] + Gp[4][m_l][u_l] + bias_i;
                float s1 = Gp[1][m_l][u_l] + Gp[5][m_l][u_l] + bias_f;
                float s2 = Gp[2][m_l][u_l] + Gp[6][m_l][u_l] + bias_g;
                float s3 = Gp[3][m_l][u_l] + Gp[7][m_l][u_l] + bias_o;
                float ii = 1.f / (1.f + expf(-s0));
                float ff = 1.f / (1.f + expf(-s1));
                float gv = tanhf(s2);
                float oo = 1.f / (1.f + expf(-s3));
                cReg = ff * cReg + ii * gv;
                float hn = oo * tanhf(cReg);
                unsigned short hb16 = bf16r(hn);

                float hn_p = __shfl_xor(hn, 1);
                if (role == 0) {
                    // local tagged (plain store -> local L2)
                    volatile unsigned int* lp = h0loc + grp * 65536
                        + ((i & 7) << 13) + m_l * 512 + ucell;
                    *lp = ((unsigned int)(i + 1) << 16) | (unsigned int)hb16;
                    // truth copy (sc1, packed pair)
                    if ((u_l & 1) == 0) {
                        unsigned short* xbuf = h0x + ((i & 7) << 15);
                        st_h32((unsigned int*)xbuf + ((bcell * 512 + ucell) >> 1),
                               pack2bf(hn, hn_p));
                    }
                } else {
                    volatile unsigned int* lp = h1loc + grp * 65536
                        + (((i - 1) & 7) << 13) + m_l * 512 + ucell;
                    *lp = ((unsigned int)i << 16) | (unsigned int)hb16;
                    if ((u_l & 1) == 0) {
                        unsigned short* xbuf = h1x + (((i - 1) & 7) << 15);
                        st_h32((unsigned int*)xbuf + ((bcell * 512 + ucell) >> 1),
                               pack2bf(hn, hn_p));
                    }
                    int s = i - 1;
                    out[(long long)bcell * (NS * NH) + (long long)s * NH + ucell] = hn;
                    if (i == NS) {
                        float* dst = out + (long long)NB * NS * NH;
                        dst[bcell * NH + ucell] = hn;
                        dst[NB * NH + bcell * NH + ucell] = cReg;
                    }
                }
            }
            __syncthreads();   // sync3: all stores drained (vmcnt per wave)
            if (tid == 0) st_flag(myflag, (unsigned int)(i + 1));

            // ---- prefetch x(i+1); latency hides into next iteration ----
            if (role == 0 && i + 1 < NS) {
                #pragma unroll
                for (int j2 = 0; j2 < 2; ++j2) {
                    int sid = j2 * 512 + tid;
                    int k = (sid >> 6) * 32 + skoff;
                    const float* s = input + (long long)(m0 + srow) * (NS * ND)
                                           + (long long)(i + 1) * ND + k;
                    xp[2 * j2]     = *(const float4*)s;
                    xp[2 * j2 + 1] = *(const float4*)(s + 4);
                }
            }
        } else {
            __syncthreads();
            if (tid == 0) st_flag(myflag, (unsigned int)(i + 1));
        }
    }
}

extern "C" void kernel_launch(void* const* d_in, const int* in_sizes, int n_in,
                              void* d_out, int out_size, void* d_ws, size_t ws_size,
                              hipStream_t stream) {
    const float* input = (const float*)d_in[0];
    const float* enc_h = (const float*)d_in[1];
    const float* enc_c = (const float*)d_in[2];
    const float* W_ih  = (const float*)d_in[3];
    const float* W_hh  = (const float*)d_in[4];
    const float* b_ih  = (const float*)d_in[5];
    const float* b_hh  = (const float*)d_in[6];
    float* out = (float*)d_out;
    unsigned char* ws = (unsigned char*)d_ws;

    unsigned short* wpk   = (unsigned short*)(ws + WPK_OFF);
    unsigned int*   h0loc = (unsigned int*)(ws + H0LOC_OFF);
    unsigned int*   h1loc = (unsigned int*)(ws + H1LOC_OFF);
    unsigned short* h0x   = (unsigned short*)(ws + H0X_OFF);
    unsigned short* h1x   = (unsigned short*)(ws + H1X_OFF);
    unsigned int*   flags = (unsigned int*)(ws + FLAGS_OFF);

    prep_weights_k<<<2048, 256, 0, stream>>>(W_ih, W_hh, (unsigned int*)wpk);
    prep_state_k<<<1024, 256, 0, stream>>>(enc_h, h0loc, h1loc, h0x, h1x, flags);
    lstm_persist_k<<<256, 512, 0, stream>>>(input, enc_c, b_ih, b_hh, wpk,
                                            h0loc, h1loc, h0x, h1x, out, flags);
}